// Round 5
// baseline (69.945 us; speedup 1.0000x reference)
//
#include <hip/hip_runtime.h>

// Problem constants (from setup_inputs: B=4, T=8192, C=1024, stride=2)
#define NB 4
#define NT 8192
#define NC 1024
#define W0C 128
#define W1C 64
#define W2C 16
#define NCHUNKS ((NT - W0C) / 2) // 4032
#define NPAIRS (W1C / 2)         // 32

// Output layout (flat f32 offsets): K0,V0,K1,V1,K2,V2,total_recon
#define OFF_K0 0
#define OFF_V0 (NB * W0C * NC)             // 524288
#define OFF_K1 (2 * NB * W0C * NC)         // 1048576
#define OFF_V1 (OFF_K1 + NB * W1C * NC)    // 1310720
#define OFF_K2 (OFF_V1 + NB * W1C * NC)    // 1572864
#define OFF_V2 (OFF_K2 + NB * W2C * NC)    // 1638400
#define OFF_R  (OFF_V2 + NB * W2C * NC)    // 1703936

// Workspace layout (floats): [0, WS_P2) pool1 partials, [WS_P2, WS_P2+128) pool2
// partials, [WS_CNT] completion counter (uint, zeroed by async memset per launch)
#define WS_P2 (NB * NCHUNKS) // 16128
#define WS_CNT 16384

#define CP_BLOCKS 256 // 2*W0C*NC/4/256 float4-copy blocks per batch

__device__ __forceinline__ float dot4(float4 a, float4 b) {
    return a.x * b.x + a.y * b.y + a.z * b.z + a.w * b.w;
}

// Thin-thread level-1 pool: one BLOCK per chunk, one float4 per array per
// thread (R2/R3/R4 showed pool1 duration is insensitive to issue structure —
// it runs at the memory system's practical rate; keep the simplest shape).
// blockIdx.x >= NCHUNKS handles the K0/V0 tail copy.
__global__ __launch_bounds__(256) void pool1_kernel(const float* __restrict__ K,
                                                    const float* __restrict__ V,
                                                    const float* __restrict__ q,
                                                    float* __restrict__ out,
                                                    float* __restrict__ ws) {
    const int b = blockIdx.y;

    if (blockIdx.x >= NCHUNKS) {
        // ---- copy K0/V0 (last W0 rows) for batch b ----
        const int i = (blockIdx.x - NCHUNKS) * 256 + threadIdx.x; // float4 idx in batch
        const int half = W0C * NC / 4;                            // 32768
        const float* src;
        float* dst;
        int r;
        if (i < half) { src = K; dst = out + OFF_K0; r = i; }
        else          { src = V; dst = out + OFF_V0; r = i - half; }
        const float4* s4 = (const float4*)(src + ((size_t)b * NT + (NT - W0C)) * NC);
        ((float4*)(dst + (size_t)b * W0C * NC))[r] = s4[r];
        return;
    }

    const int n = blockIdx.x;
    const int t = threadIdx.x;

    const size_t row0 = ((size_t)b * NT + 2 * n) * NC;
    const float4 k0 = ((const float4*)(K + row0))[t];
    const float4 k1 = ((const float4*)(K + row0 + NC))[t];
    const float4 v0 = ((const float4*)(V + row0))[t];
    const float4 v1 = ((const float4*)(V + row0 + NC))[t];
    const float4 q4 = ((const float4*)q)[t];

    float s0 = dot4(q4, k0);
    float s1 = dot4(q4, k1);
    const float4 dv = make_float4(v0.x - v1.x, v0.y - v1.y, v0.z - v1.z, v0.w - v1.w);
    float d2 = dot4(dv, dv);

    // Wave butterfly, then cross-wave combine via 12 LDS floats.
#pragma unroll
    for (int off = 1; off < 64; off <<= 1) {
        s0 += __shfl_xor(s0, off);
        s1 += __shfl_xor(s1, off);
        d2 += __shfl_xor(d2, off);
    }

    __shared__ float lds[12];
    const int lane = t & 63, wv = t >> 6;
    if (lane == 0) { lds[wv] = s0; lds[4 + wv] = s1; lds[8 + wv] = d2; }
    __syncthreads();
    const float t0 = lds[0] + lds[1] + lds[2] + lds[3];
    const float t1 = lds[4] + lds[5] + lds[6] + lds[7];
    const float td = lds[8] + lds[9] + lds[10] + lds[11];
    const float w0 = 1.0f / (1.0f + __expf(t1 - t0)); // softmax over 2

    if (t == 0) {
        const float dw = w0 - 0.5f;
        ws[b * NCHUNKS + n] = dw * dw * td; // unscaled; scaled in final reduce
    }

    if (n >= NCHUNKS - W1C) {
        const float w1 = 1.0f - w0;
        const int nn = n - (NCHUNKS - W1C);
        float4* skp = (float4*)(out + OFF_K1 + ((size_t)b * W1C + nn) * NC);
        float4* svp = (float4*)(out + OFF_V1 + ((size_t)b * W1C + nn) * NC);
        skp[t] = make_float4(w0 * k0.x + w1 * k1.x, w0 * k0.y + w1 * k1.y,
                             w0 * k0.z + w1 * k1.z, w0 * k0.w + w1 * k1.w);
        svp[t] = make_float4(w0 * v0.x + w1 * v1.x, w0 * v0.y + w1 * v1.y,
                             w0 * v0.z + w1 * v1.z, w0 * v0.w + w1 * v1.w);
    }
}

// Fused level-2 pool + final reduction. 32 blocks: block j = pair j, wave wv =
// batch wv. Last block to finish (threadfence reduction pattern) sums all
// partials and writes total_recon — removes the separate reduce dispatch.
__global__ __launch_bounds__(256) void pool2r_kernel(const float* __restrict__ q,
                                                     float* __restrict__ out,
                                                     float* __restrict__ ws) {
    const int j = blockIdx.x;          // pair index, 0..31
    const int b = threadIdx.x >> 6;    // batch = wave id
    const int lane = threadIdx.x & 63;

    const float* K1 = out + OFF_K1;
    const float* V1 = out + OFF_V1;
    const size_t row0 = ((size_t)b * W1C + 2 * j) * NC;
    const float4* Kp0 = (const float4*)(K1 + row0);
    const float4* Kp1 = (const float4*)(K1 + row0 + NC);
    const float4* Vp0 = (const float4*)(V1 + row0);
    const float4* Vp1 = (const float4*)(V1 + row0 + NC);
    const float4* q4 = (const float4*)(q + NC); // q_pool[1]

    float4 k0[4], k1[4], v0[4], v1[4], qv[4];
#pragma unroll
    for (int m = 0; m < 4; m++) {
        const int idx = lane + 64 * m;
        k0[m] = Kp0[idx]; k1[m] = Kp1[idx];
        v0[m] = Vp0[idx]; v1[m] = Vp1[idx];
        qv[m] = q4[idx];
    }

    float s0 = 0.f, s1 = 0.f, d2 = 0.f;
#pragma unroll
    for (int m = 0; m < 4; m++) {
        s0 += dot4(qv[m], k0[m]);
        s1 += dot4(qv[m], k1[m]);
        float4 dv = make_float4(v0[m].x - v1[m].x, v0[m].y - v1[m].y,
                                v0[m].z - v1[m].z, v0[m].w - v1[m].w);
        d2 += dot4(dv, dv);
    }

#pragma unroll
    for (int off = 1; off < 64; off <<= 1) {
        s0 += __shfl_xor(s0, off);
        s1 += __shfl_xor(s1, off);
        d2 += __shfl_xor(d2, off);
    }

    const float w0 = 1.0f / (1.0f + __expf(s1 - s0));
    if (lane == 0) {
        const float dw = w0 - 0.5f;
        ws[WS_P2 + b * NPAIRS + j] = dw * dw * d2;
    }

    if (j >= NPAIRS - W2C) {
        const float w1 = 1.0f - w0;
        const int nn = j - (NPAIRS - W2C);
        float4* skp = (float4*)(out + OFF_K2 + ((size_t)b * W2C + nn) * NC);
        float4* svp = (float4*)(out + OFF_V2 + ((size_t)b * W2C + nn) * NC);
#pragma unroll
        for (int m = 0; m < 4; m++) {
            const int idx = lane + 64 * m;
            skp[idx] = make_float4(w0 * k0[m].x + w1 * k1[m].x, w0 * k0[m].y + w1 * k1[m].y,
                                   w0 * k0[m].z + w1 * k1[m].z, w0 * k0[m].w + w1 * k1[m].w);
            svp[idx] = make_float4(w0 * v0[m].x + w1 * v1[m].x, w0 * v0[m].y + w1 * v1[m].y,
                                   w0 * v0[m].z + w1 * v1[m].z, w0 * v0[m].w + w1 * v1[m].w);
        }
    }

    // ---- last-block-done final reduction (canonical threadfence pattern) ----
    __syncthreads(); // all stores in this block issued & drained (vmcnt before barrier)
    __shared__ int is_last;
    if (threadIdx.x == 0) {
        __threadfence(); // release: make this block's ws partial device-visible
        unsigned prev = atomicAdd((unsigned int*)(ws + WS_CNT), 1u);
        is_last = (prev == 31u);
    }
    __syncthreads();
    if (!is_last) return;

    __threadfence(); // acquire: observe all other blocks' partials
    const int tid = threadIdx.x;
    float acc1 = 0.f;
    for (int i = tid; i < WS_P2; i += 256) acc1 += ws[i];
    float acc2 = 0.f;
    for (int i = tid; i < NB * NPAIRS; i += 256) acc2 += ws[WS_P2 + i];

    const float S1 = 1.0f / ((float)NB * NC * NCHUNKS);
    const float S2 = 0.5f / ((float)NB * NC);
    float acc = acc1 * S1 + acc2 * S2;

#pragma unroll
    for (int off = 32; off > 0; off >>= 1) acc += __shfl_down(acc, off);

    __shared__ float red[4];
    if ((tid & 63) == 0) red[tid >> 6] = acc;
    __syncthreads();
    if (tid == 0) out[OFF_R] = red[0] + red[1] + red[2] + red[3];
}

extern "C" void kernel_launch(void* const* d_in, const int* in_sizes, int n_in,
                              void* d_out, int out_size, void* d_ws, size_t ws_size,
                              hipStream_t stream) {
    const float* K = (const float*)d_in[0];
    const float* V = (const float*)d_in[1];
    const float* q = (const float*)d_in[2];
    float* out = (float*)d_out;
    float* ws = (float*)d_ws;

    // zero the completion counter (graph-capture-safe async memset)
    hipMemsetAsync((char*)d_ws + (size_t)WS_CNT * sizeof(float), 0, sizeof(unsigned int), stream);

    pool1_kernel<<<dim3(NCHUNKS + CP_BLOCKS, NB), 256, 0, stream>>>(K, V, q, out, ws);
    pool2r_kernel<<<dim3(NPAIRS), 256, 0, stream>>>(q, out, ws);
}

// Round 6
// 61.638 us; speedup vs baseline: 1.1348x; 1.1348x over previous
//
#include <hip/hip_runtime.h>

// Problem constants (from setup_inputs: B=4, T=8192, C=1024, stride=2)
#define NB 4
#define NT 8192
#define NC 1024
#define W0C 128
#define W1C 64
#define W2C 16
#define NCHUNKS ((NT - W0C) / 2) // 4032
#define NPAIRS (W1C / 2)         // 32
#define NREG (NCHUNKS - W1C)     // 3968 single-chunk blocks per batch
#define NPB NPAIRS               // 32 pair blocks per batch (2 tail chunks each)

// Output layout (flat f32 offsets): K0,V0,K1,V1,K2,V2,total_recon
#define OFF_K0 0
#define OFF_V0 (NB * W0C * NC)             // 524288
#define OFF_K1 (2 * NB * W0C * NC)         // 1048576
#define OFF_V1 (OFF_K1 + NB * W1C * NC)    // 1310720
#define OFF_K2 (OFF_V1 + NB * W1C * NC)    // 1572864
#define OFF_V2 (OFF_K2 + NB * W2C * NC)    // 1638400
#define OFF_R  (OFF_V2 + NB * W2C * NC)    // 1703936

// Workspace: per-batch WS_STRIDE pre-scaled recon partials (all slots written
// every launch -> no zeroing, no atomics, deterministic reduce).
#define WS_STRIDE (NREG + NPB) // 4000

#define CP_BLOCKS 256 // 2*W0C*NC/4/256 float4-copy blocks per batch

#define S1F (1.0f / ((float)NB * NC * NCHUNKS))
#define S2F (0.5f / ((float)NB * NC))

__device__ __forceinline__ float dot4(float4 a, float4 b) {
    return a.x * b.x + a.y * b.y + a.z * b.z + a.w * b.w;
}
__device__ __forceinline__ float4 lerp4(float w0, float4 a, float w1, float4 b) {
    return make_float4(w0 * a.x + w1 * b.x, w0 * a.y + w1 * b.y,
                       w0 * a.z + w1 * b.z, w0 * a.w + w1 * b.w);
}
__device__ __forceinline__ float4 sub4(float4 a, float4 b) {
    return make_float4(a.x - b.x, a.y - b.y, a.z - b.z, a.w - b.w);
}

// One kernel, three block roles along x:
//   [0, NREG)            single-chunk level-1 pool (recon partial only)
//   [NREG, NREG+NPB)     pair block: 2 tail chunks -> K1/V1 rows AND the
//                        level-2 pool on them in-register -> K2/V2 + recon2
//   [NREG+NPB, +CP)      K0/V0 tail copy
__global__ __launch_bounds__(256) void pool1_kernel(const float* __restrict__ K,
                                                    const float* __restrict__ V,
                                                    const float* __restrict__ q,
                                                    float* __restrict__ out,
                                                    float* __restrict__ ws) {
    const int b = blockIdx.y;
    const int x = blockIdx.x;
    const int t = threadIdx.x;

    if (x >= NREG + NPB) {
        // ---- copy K0/V0 (last W0 rows) for batch b ----
        const int i = (x - (NREG + NPB)) * 256 + t; // float4 idx in batch
        const int half = W0C * NC / 4;              // 32768
        const float* src;
        float* dst;
        int r;
        if (i < half) { src = K; dst = out + OFF_K0; r = i; }
        else          { src = V; dst = out + OFF_V0; r = i - half; }
        const float4* s4 = (const float4*)(src + ((size_t)b * NT + (NT - W0C)) * NC);
        ((float4*)(dst + (size_t)b * W0C * NC))[r] = s4[r];
        return;
    }

    __shared__ float lds[24];
    const int lane = t & 63, wv = t >> 6;

    if (x < NREG) {
        // ---- single-chunk level-1 pool (no K1/V1 output) ----
        const int n = x;
        const size_t row0 = ((size_t)b * NT + 2 * n) * NC;
        const float4 k0 = ((const float4*)(K + row0))[t];
        const float4 k1 = ((const float4*)(K + row0 + NC))[t];
        const float4 v0 = ((const float4*)(V + row0))[t];
        const float4 v1 = ((const float4*)(V + row0 + NC))[t];
        const float4 q4 = ((const float4*)q)[t];

        float s0 = dot4(q4, k0);
        float s1 = dot4(q4, k1);
        const float4 dv = sub4(v0, v1);
        float d2 = dot4(dv, dv);

#pragma unroll
        for (int off = 1; off < 64; off <<= 1) {
            s0 += __shfl_xor(s0, off);
            s1 += __shfl_xor(s1, off);
            d2 += __shfl_xor(d2, off);
        }
        if (lane == 0) { lds[wv] = s0; lds[4 + wv] = s1; lds[8 + wv] = d2; }
        __syncthreads();
        if (t == 0) {
            const float t0 = lds[0] + lds[1] + lds[2] + lds[3];
            const float t1 = lds[4] + lds[5] + lds[6] + lds[7];
            const float td = lds[8] + lds[9] + lds[10] + lds[11];
            const float w0 = 1.0f / (1.0f + __expf(t1 - t0));
            const float dw = w0 - 0.5f;
            ws[b * WS_STRIDE + n] = S1F * dw * dw * td; // pre-scaled
        }
        return;
    }

    // ---- pair block: tail chunks n0=NREG+2m, n0+1 (4 contiguous rows) ----
    const int m = x - NREG; // 0..31
    const size_t r0 = ((size_t)b * NT + 2 * (NREG + 2 * m)) * NC;
    const float4 ka0 = ((const float4*)(K + r0))[t];
    const float4 ka1 = ((const float4*)(K + r0 + NC))[t];
    const float4 kb0 = ((const float4*)(K + r0 + 2 * NC))[t];
    const float4 kb1 = ((const float4*)(K + r0 + 3 * NC))[t];
    const float4 va0 = ((const float4*)(V + r0))[t];
    const float4 va1 = ((const float4*)(V + r0 + NC))[t];
    const float4 vb0 = ((const float4*)(V + r0 + 2 * NC))[t];
    const float4 vb1 = ((const float4*)(V + r0 + 3 * NC))[t];
    const float4 q0 = ((const float4*)q)[t];
    const float4 q1 = ((const float4*)(q + NC))[t]; // q_pool[1]

    // Level-1 partials for both chunks
    float sa0 = dot4(q0, ka0), sa1 = dot4(q0, ka1);
    float sb0 = dot4(q0, kb0), sb1 = dot4(q0, kb1);
    const float4 dva = sub4(va0, va1);
    const float4 dvb = sub4(vb0, vb1);
    float d2a = dot4(dva, dva), d2b = dot4(dvb, dvb);

#pragma unroll
    for (int off = 1; off < 64; off <<= 1) {
        sa0 += __shfl_xor(sa0, off);
        sa1 += __shfl_xor(sa1, off);
        sb0 += __shfl_xor(sb0, off);
        sb1 += __shfl_xor(sb1, off);
        d2a += __shfl_xor(d2a, off);
        d2b += __shfl_xor(d2b, off);
    }
    if (lane == 0) {
        lds[wv] = sa0; lds[4 + wv] = sa1;
        lds[8 + wv] = sb0; lds[12 + wv] = sb1;
        lds[16 + wv] = d2a; lds[20 + wv] = d2b;
    }
    __syncthreads();
    const float Ta0 = lds[0] + lds[1] + lds[2] + lds[3];
    const float Ta1 = lds[4] + lds[5] + lds[6] + lds[7];
    const float Tb0 = lds[8] + lds[9] + lds[10] + lds[11];
    const float Tb1 = lds[12] + lds[13] + lds[14] + lds[15];
    const float Tda = lds[16] + lds[17] + lds[18] + lds[19];
    const float Tdb = lds[20] + lds[21] + lds[22] + lds[23];

    const float wa = 1.0f / (1.0f + __expf(Ta1 - Ta0));
    const float wb = 1.0f / (1.0f + __expf(Tb1 - Tb0));

    const float4 ska = lerp4(wa, ka0, 1.0f - wa, ka1);
    const float4 sva = lerp4(wa, va0, 1.0f - wa, va1);
    const float4 skb = lerp4(wb, kb0, 1.0f - wb, kb1);
    const float4 svb = lerp4(wb, vb0, 1.0f - wb, vb1);

    // K1/V1 rows 2m, 2m+1
    {
        float4* k1p = (float4*)(out + OFF_K1 + ((size_t)b * W1C + 2 * m) * NC);
        float4* v1p = (float4*)(out + OFF_V1 + ((size_t)b * W1C + 2 * m) * NC);
        k1p[t] = ska; k1p[t + NC / 4] = skb;
        v1p[t] = sva; v1p[t + NC / 4] = svb;
    }

    // Level-2 pool on (ska,skb)/(sva,svb) with q_pool[1]
    float s20 = dot4(q1, ska), s21 = dot4(q1, skb);
    const float4 dsv = sub4(sva, svb);
    float d22 = dot4(dsv, dsv);
#pragma unroll
    for (int off = 1; off < 64; off <<= 1) {
        s20 += __shfl_xor(s20, off);
        s21 += __shfl_xor(s21, off);
        d22 += __shfl_xor(d22, off);
    }
    __syncthreads(); // phase-1 lds fully consumed before overwrite
    if (lane == 0) { lds[wv] = s20; lds[4 + wv] = s21; lds[8 + wv] = d22; }
    __syncthreads();
    const float T20 = lds[0] + lds[1] + lds[2] + lds[3];
    const float T21 = lds[4] + lds[5] + lds[6] + lds[7];
    const float T22 = lds[8] + lds[9] + lds[10] + lds[11];
    const float u0 = 1.0f / (1.0f + __expf(T21 - T20));

    if (t == 0) {
        const float dwa = wa - 0.5f, dwb = wb - 0.5f, du = u0 - 0.5f;
        ws[b * WS_STRIDE + NREG + m] =
            S1F * (dwa * dwa * Tda + dwb * dwb * Tdb) + S2F * du * du * T22;
    }

    if (m >= NPAIRS - W2C) {
        const int nn = m - (NPAIRS - W2C);
        float4* k2p = (float4*)(out + OFF_K2 + ((size_t)b * W2C + nn) * NC);
        float4* v2p = (float4*)(out + OFF_V2 + ((size_t)b * W2C + nn) * NC);
        k2p[t] = lerp4(u0, ska, 1.0f - u0, skb);
        v2p[t] = lerp4(u0, sva, 1.0f - u0, svb);
    }
}

// Final reduce: one block sums the 16000 pre-scaled partials (deterministic).
__global__ __launch_bounds__(256) void reduce_kernel(const float* __restrict__ ws,
                                                     float* __restrict__ out) {
    const int tid = threadIdx.x;
    float acc = 0.f;
    for (int i = tid; i < NB * WS_STRIDE; i += 256) acc += ws[i];

#pragma unroll
    for (int off = 32; off > 0; off >>= 1) acc += __shfl_down(acc, off);

    __shared__ float red[4];
    if ((tid & 63) == 0) red[tid >> 6] = acc;
    __syncthreads();
    if (tid == 0) out[OFF_R] = red[0] + red[1] + red[2] + red[3];
}

extern "C" void kernel_launch(void* const* d_in, const int* in_sizes, int n_in,
                              void* d_out, int out_size, void* d_ws, size_t ws_size,
                              hipStream_t stream) {
    const float* K = (const float*)d_in[0];
    const float* V = (const float*)d_in[1];
    const float* q = (const float*)d_in[2];
    float* out = (float*)d_out;
    float* ws = (float*)d_ws;

    pool1_kernel<<<dim3(NREG + NPB + CP_BLOCKS, NB), 256, 0, stream>>>(K, V, q, out, ws);
    reduce_kernel<<<1, 256, 0, stream>>>(ws, out);
}

// Round 7
// 49.393 us; speedup vs baseline: 1.4161x; 1.2479x over previous
//
#include <hip/hip_runtime.h>

// Problem constants (from setup_inputs: B=4, T=8192, C=1024, stride=2)
#define NB 4
#define NT 8192
#define NC 1024
#define W0C 128
#define W1C 64
#define W2C 16
#define NCHUNKS ((NT - W0C) / 2) // 4032
#define NPAIRS (W1C / 2)         // 32
#define NREG (NCHUNKS - W1C)     // 3968 regular chunks per batch
#define ITERS 8
#define RB (NREG / ITERS)        // 496 range blocks per batch
#define NPB NPAIRS               // 32 pair blocks per batch
#define CPB 64                   // copy blocks per batch (4 float4 iters each)

// Output layout (flat f32 offsets): K0,V0,K1,V1,K2,V2,total_recon
#define OFF_K0 0
#define OFF_V0 (NB * W0C * NC)             // 524288
#define OFF_K1 (2 * NB * W0C * NC)         // 1048576
#define OFF_V1 (OFF_K1 + NB * W1C * NC)    // 1310720
#define OFF_K2 (OFF_V1 + NB * W1C * NC)    // 1572864
#define OFF_V2 (OFF_K2 + NB * W2C * NC)    // 1638400
#define OFF_R  (OFF_V2 + NB * W2C * NC)    // 1703936

// Workspace: per-batch WS_STRIDE pre-scaled recon partials (every slot written
// every launch -> no zeroing, no atomics, deterministic final reduce).
#define WS_STRIDE (RB + NPB) // 528

#define S1F (1.0f / ((float)NB * NC * NCHUNKS))
#define S2F (0.5f / ((float)NB * NC))

__device__ __forceinline__ float dot4(float4 a, float4 b) {
    return a.x * b.x + a.y * b.y + a.z * b.z + a.w * b.w;
}
__device__ __forceinline__ float4 lerp4(float w0, float4 a, float w1, float4 b) {
    return make_float4(w0 * a.x + w1 * b.x, w0 * a.y + w1 * b.y,
                       w0 * a.z + w1 * b.z, w0 * a.w + w1 * b.w);
}
__device__ __forceinline__ float4 sub4(float4 a, float4 b) {
    return make_float4(a.x - b.x, a.y - b.y, a.z - b.z, a.w - b.w);
}

// One kernel, three block roles along x:
//   [0, RB)                 range block: 8 consecutive chunks, register
//                           double-buffered prefetch (loads of chunk i+1
//                           overlap the reduce chain of chunk i); only the
//                           recon partial is produced (no K1/V1 rows here).
//   [RB, RB+NPB)            pair block: 2 tail chunks -> K1/V1 rows AND the
//                           level-2 pool in-register -> K2/V2 + recon2.
//   [RB+NPB, RB+NPB+CPB)    K0/V0 tail copy (4 float4 per thread).
__global__ __launch_bounds__(256) void pool1_kernel(const float* __restrict__ K,
                                                    const float* __restrict__ V,
                                                    const float* __restrict__ q,
                                                    float* __restrict__ out,
                                                    float* __restrict__ ws) {
    const int b = blockIdx.y;
    const int x = blockIdx.x;
    const int t = threadIdx.x;

    __shared__ float lds[24];
    const int lane = t & 63, wv = t >> 6;

    if (x < RB) {
        // ---- range block: chunks [x*ITERS, (x+1)*ITERS) of batch b ----
        const float4 q4 = ((const float4*)q)[t];
        const size_t base = ((size_t)b * NT + 2 * x * ITERS) * NC;
        const float4* Kp = (const float4*)(K + base); // row stride NC/4 = 256
        const float4* Vp = (const float4*)(V + base);

        float4 k0 = Kp[t], k1 = Kp[t + 256];
        float4 v0 = Vp[t], v1 = Vp[t + 256];
        float racc = 0.f;

        for (int i = 0; i < ITERS; ++i) {
            float4 nk0, nk1, nv0, nv1;
            if (i + 1 < ITERS) {
                const int ro = (i + 1) * 512; // 2 rows * 256 float4
                nk0 = Kp[t + ro]; nk1 = Kp[t + ro + 256];
                nv0 = Vp[t + ro]; nv1 = Vp[t + ro + 256];
            }
            // e = s0 - s1 (only the difference feeds the 2-way softmax)
            float e = dot4(q4, sub4(k0, k1));
            const float4 dv = sub4(v0, v1);
            float d2 = dot4(dv, dv);
#pragma unroll
            for (int off = 1; off < 64; off <<= 1) {
                e += __shfl_xor(e, off);
                d2 += __shfl_xor(d2, off);
            }
            const int pb = (i & 1) * 8; // LDS parity buffer
            if (lane == 0) { lds[pb + wv] = e; lds[pb + 4 + wv] = d2; }
            __syncthreads();
            if (t == 0) {
                const float te = lds[pb] + lds[pb + 1] + lds[pb + 2] + lds[pb + 3];
                const float td = lds[pb + 4] + lds[pb + 5] + lds[pb + 6] + lds[pb + 7];
                const float w0 = 1.0f / (1.0f + __expf(-te)); // sigma(s0-s1)
                const float dw = w0 - 0.5f;
                racc += dw * dw * td;
            }
            k0 = nk0; k1 = nk1; v0 = nv0; v1 = nv1;
        }
        if (t == 0) ws[b * WS_STRIDE + x] = S1F * racc;
        return;
    }

    if (x >= RB + NPB) {
        // ---- copy K0/V0 (last W0 rows) for batch b ----
        const int ci = x - (RB + NPB); // 0..CPB-1
        const int half = W0C * NC / 4; // 32768 float4 per tensor per batch
        const float4* Ks = (const float4*)(K + ((size_t)b * NT + (NT - W0C)) * NC);
        const float4* Vs = (const float4*)(V + ((size_t)b * NT + (NT - W0C)) * NC);
        float4* K0d = (float4*)(out + OFF_K0 + (size_t)b * W0C * NC);
        float4* V0d = (float4*)(out + OFF_V0 + (size_t)b * W0C * NC);
#pragma unroll
        for (int it = 0; it < 4; ++it) {
            const int i = (it * CPB + ci) * 256 + t; // 0..65535
            if (i < half) K0d[i] = Ks[i];
            else          V0d[i - half] = Vs[i - half];
        }
        return;
    }

    // ---- pair block: tail chunks NREG+2m, NREG+2m+1 (4 contiguous rows) ----
    const int m = x - RB; // 0..31
    const size_t r0 = ((size_t)b * NT + 2 * (NREG + 2 * m)) * NC;
    const float4 ka0 = ((const float4*)(K + r0))[t];
    const float4 ka1 = ((const float4*)(K + r0 + NC))[t];
    const float4 kb0 = ((const float4*)(K + r0 + 2 * NC))[t];
    const float4 kb1 = ((const float4*)(K + r0 + 3 * NC))[t];
    const float4 va0 = ((const float4*)(V + r0))[t];
    const float4 va1 = ((const float4*)(V + r0 + NC))[t];
    const float4 vb0 = ((const float4*)(V + r0 + 2 * NC))[t];
    const float4 vb1 = ((const float4*)(V + r0 + 3 * NC))[t];
    const float4 q0 = ((const float4*)q)[t];
    const float4 q1 = ((const float4*)(q + NC))[t]; // q_pool[1]

    // Level-1 partials for both chunks
    float sa0 = dot4(q0, ka0), sa1 = dot4(q0, ka1);
    float sb0 = dot4(q0, kb0), sb1 = dot4(q0, kb1);
    const float4 dva = sub4(va0, va1);
    const float4 dvb = sub4(vb0, vb1);
    float d2a = dot4(dva, dva), d2b = dot4(dvb, dvb);

#pragma unroll
    for (int off = 1; off < 64; off <<= 1) {
        sa0 += __shfl_xor(sa0, off);
        sa1 += __shfl_xor(sa1, off);
        sb0 += __shfl_xor(sb0, off);
        sb1 += __shfl_xor(sb1, off);
        d2a += __shfl_xor(d2a, off);
        d2b += __shfl_xor(d2b, off);
    }
    if (lane == 0) {
        lds[wv] = sa0; lds[4 + wv] = sa1;
        lds[8 + wv] = sb0; lds[12 + wv] = sb1;
        lds[16 + wv] = d2a; lds[20 + wv] = d2b;
    }
    __syncthreads();
    const float Ta0 = lds[0] + lds[1] + lds[2] + lds[3];
    const float Ta1 = lds[4] + lds[5] + lds[6] + lds[7];
    const float Tb0 = lds[8] + lds[9] + lds[10] + lds[11];
    const float Tb1 = lds[12] + lds[13] + lds[14] + lds[15];
    const float Tda = lds[16] + lds[17] + lds[18] + lds[19];
    const float Tdb = lds[20] + lds[21] + lds[22] + lds[23];

    const float wa = 1.0f / (1.0f + __expf(Ta1 - Ta0));
    const float wb = 1.0f / (1.0f + __expf(Tb1 - Tb0));

    const float4 ska = lerp4(wa, ka0, 1.0f - wa, ka1);
    const float4 sva = lerp4(wa, va0, 1.0f - wa, va1);
    const float4 skb = lerp4(wb, kb0, 1.0f - wb, kb1);
    const float4 svb = lerp4(wb, vb0, 1.0f - wb, vb1);

    // K1/V1 rows 2m, 2m+1
    {
        float4* k1p = (float4*)(out + OFF_K1 + ((size_t)b * W1C + 2 * m) * NC);
        float4* v1p = (float4*)(out + OFF_V1 + ((size_t)b * W1C + 2 * m) * NC);
        k1p[t] = ska; k1p[t + NC / 4] = skb;
        v1p[t] = sva; v1p[t + NC / 4] = svb;
    }

    // Level-2 pool on (ska,skb)/(sva,svb) with q_pool[1]
    float e2 = dot4(q1, sub4(ska, skb));
    const float4 dsv = sub4(sva, svb);
    float d22 = dot4(dsv, dsv);
#pragma unroll
    for (int off = 1; off < 64; off <<= 1) {
        e2 += __shfl_xor(e2, off);
        d22 += __shfl_xor(d22, off);
    }
    __syncthreads(); // phase-1 lds fully consumed before overwrite
    if (lane == 0) { lds[wv] = e2; lds[4 + wv] = d22; }
    __syncthreads();
    const float Te2 = lds[0] + lds[1] + lds[2] + lds[3];
    const float Td2 = lds[4] + lds[5] + lds[6] + lds[7];
    const float u0 = 1.0f / (1.0f + __expf(-Te2));

    if (t == 0) {
        const float dwa = wa - 0.5f, dwb = wb - 0.5f, du = u0 - 0.5f;
        ws[b * WS_STRIDE + RB + m] =
            S1F * (dwa * dwa * Tda + dwb * dwb * Tdb) + S2F * du * du * Td2;
    }

    if (m >= NPAIRS - W2C) {
        const int nn = m - (NPAIRS - W2C);
        float4* k2p = (float4*)(out + OFF_K2 + ((size_t)b * W2C + nn) * NC);
        float4* v2p = (float4*)(out + OFF_V2 + ((size_t)b * W2C + nn) * NC);
        k2p[t] = lerp4(u0, ska, 1.0f - u0, skb);
        v2p[t] = lerp4(u0, sva, 1.0f - u0, svb);
    }
}

// Final reduce: one block sums the 2112 pre-scaled partials (deterministic).
__global__ __launch_bounds__(256) void reduce_kernel(const float* __restrict__ ws,
                                                     float* __restrict__ out) {
    const int tid = threadIdx.x;
    float acc = 0.f;
    for (int i = tid; i < NB * WS_STRIDE; i += 256) acc += ws[i];

#pragma unroll
    for (int off = 32; off > 0; off >>= 1) acc += __shfl_down(acc, off);

    __shared__ float red[4];
    if ((tid & 63) == 0) red[tid >> 6] = acc;
    __syncthreads();
    if (tid == 0) out[OFF_R] = red[0] + red[1] + red[2] + red[3];
}

extern "C" void kernel_launch(void* const* d_in, const int* in_sizes, int n_in,
                              void* d_out, int out_size, void* d_ws, size_t ws_size,
                              hipStream_t stream) {
    const float* K = (const float*)d_in[0];
    const float* V = (const float*)d_in[1];
    const float* q = (const float*)d_in[2];
    float* out = (float*)d_out;
    float* ws = (float*)d_ws;

    pool1_kernel<<<dim3(RB + NPB + CPB, NB), 256, 0, stream>>>(K, V, q, out, ws);
    reduce_kernel<<<1, 256, 0, stream>>>(ws, out);
}

// Round 8
// 48.270 us; speedup vs baseline: 1.4490x; 1.0233x over previous
//
#include <hip/hip_runtime.h>

// Problem constants (from setup_inputs: B=4, T=8192, C=1024, stride=2)
#define NB 4
#define NT 8192
#define NC 1024
#define W0C 128
#define W1C 64
#define W2C 16
#define NCHUNKS ((NT - W0C) / 2) // 4032
#define NPAIRS (W1C / 2)         // 32
#define NREG (NCHUNKS - W1C)     // 3968 regular chunks per batch
#define ITERS 16
#define RB (NREG / ITERS)        // 248 range blocks per batch
#define NPB NPAIRS               // 32 pair blocks per batch
#define CPB 64                   // copy blocks per batch (4 float4 iters each)
// grid = 4*(248+32+64) = 1376 blocks <= 2048 residency capacity (8 blocks/CU
// at VGPR<=64) -> whole grid co-resident, no over-subscription tail (R7's 2368
// -block grid paid ~320 deferred blocks ~= 5 us).

// Output layout (flat f32 offsets): K0,V0,K1,V1,K2,V2,total_recon
#define OFF_K0 0
#define OFF_V0 (NB * W0C * NC)             // 524288
#define OFF_K1 (2 * NB * W0C * NC)         // 1048576
#define OFF_V1 (OFF_K1 + NB * W1C * NC)    // 1310720
#define OFF_K2 (OFF_V1 + NB * W1C * NC)    // 1572864
#define OFF_V2 (OFF_K2 + NB * W2C * NC)    // 1638400
#define OFF_R  (OFF_V2 + NB * W2C * NC)    // 1703936

// Workspace: per-batch WS_STRIDE pre-scaled recon partials (every slot written
// every launch -> no zeroing, no atomics, deterministic final reduce).
#define WS_STRIDE (RB + NPB) // 280

#define S1F (1.0f / ((float)NB * NC * NCHUNKS))
#define S2F (0.5f / ((float)NB * NC))

__device__ __forceinline__ float dot4(float4 a, float4 b) {
    return a.x * b.x + a.y * b.y + a.z * b.z + a.w * b.w;
}
__device__ __forceinline__ float4 lerp4(float w0, float4 a, float w1, float4 b) {
    return make_float4(w0 * a.x + w1 * b.x, w0 * a.y + w1 * b.y,
                       w0 * a.z + w1 * b.z, w0 * a.w + w1 * b.w);
}
__device__ __forceinline__ float4 sub4(float4 a, float4 b) {
    return make_float4(a.x - b.x, a.y - b.y, a.z - b.z, a.w - b.w);
}

// One kernel, three block roles along x:
//   [0, RB)                 range block: 16 consecutive chunks, register
//                           double-buffered prefetch (loads of chunk i+1
//                           overlap the reduce chain of chunk i).
//   [RB, RB+NPB)            pair block: 2 tail chunks -> K1/V1 rows AND the
//                           level-2 pool in-register -> K2/V2 + recon2.
//   [RB+NPB, RB+NPB+CPB)    K0/V0 tail copy (4 float4 per thread).
__global__ __launch_bounds__(256) void pool1_kernel(const float* __restrict__ K,
                                                    const float* __restrict__ V,
                                                    const float* __restrict__ q,
                                                    float* __restrict__ out,
                                                    float* __restrict__ ws) {
    const int b = blockIdx.y;
    const int x = blockIdx.x;
    const int t = threadIdx.x;

    __shared__ float lds[24];
    const int lane = t & 63, wv = t >> 6;

    if (x < RB) {
        // ---- range block: chunks [x*ITERS, (x+1)*ITERS) of batch b ----
        const float4 q4 = ((const float4*)q)[t];
        const size_t base = ((size_t)b * NT + 2 * (size_t)x * ITERS) * NC;
        const float4* Kp = (const float4*)(K + base); // row stride NC/4 = 256
        const float4* Vp = (const float4*)(V + base);

        float4 k0 = Kp[t], k1 = Kp[t + 256];
        float4 v0 = Vp[t], v1 = Vp[t + 256];
        float racc = 0.f;

        for (int i = 0; i < ITERS; ++i) {
            float4 nk0, nk1, nv0, nv1;
            if (i + 1 < ITERS) {
                const int ro = (i + 1) * 512; // 2 rows * 256 float4
                nk0 = Kp[t + ro]; nk1 = Kp[t + ro + 256];
                nv0 = Vp[t + ro]; nv1 = Vp[t + ro + 256];
            }
            // e = s0 - s1 (only the difference feeds the 2-way softmax)
            float e = dot4(q4, sub4(k0, k1));
            const float4 dv = sub4(v0, v1);
            float d2 = dot4(dv, dv);
#pragma unroll
            for (int off = 1; off < 64; off <<= 1) {
                e += __shfl_xor(e, off);
                d2 += __shfl_xor(d2, off);
            }
            const int pb = (i & 1) * 8; // LDS parity buffer
            if (lane == 0) { lds[pb + wv] = e; lds[pb + 4 + wv] = d2; }
            __syncthreads();
            if (t == 0) {
                const float te = lds[pb] + lds[pb + 1] + lds[pb + 2] + lds[pb + 3];
                const float td = lds[pb + 4] + lds[pb + 5] + lds[pb + 6] + lds[pb + 7];
                const float w0 = 1.0f / (1.0f + __expf(-te)); // sigma(s0-s1)
                const float dw = w0 - 0.5f;
                racc += dw * dw * td;
            }
            k0 = nk0; k1 = nk1; v0 = nv0; v1 = nv1;
        }
        if (t == 0) ws[b * WS_STRIDE + x] = S1F * racc;
        return;
    }

    if (x >= RB + NPB) {
        // ---- copy K0/V0 (last W0 rows) for batch b ----
        const int ci = x - (RB + NPB); // 0..CPB-1
        const int half = W0C * NC / 4; // 32768 float4 per tensor per batch
        const float4* Ks = (const float4*)(K + ((size_t)b * NT + (NT - W0C)) * NC);
        const float4* Vs = (const float4*)(V + ((size_t)b * NT + (NT - W0C)) * NC);
        float4* K0d = (float4*)(out + OFF_K0 + (size_t)b * W0C * NC);
        float4* V0d = (float4*)(out + OFF_V0 + (size_t)b * W0C * NC);
#pragma unroll
        for (int it = 0; it < 4; ++it) {
            const int i = (it * CPB + ci) * 256 + t; // 0..65535
            if (i < half) K0d[i] = Ks[i];
            else          V0d[i - half] = Vs[i - half];
        }
        return;
    }

    // ---- pair block: tail chunks NREG+2m, NREG+2m+1 (4 contiguous rows) ----
    const int m = x - RB; // 0..31
    const size_t r0 = ((size_t)b * NT + 2 * (NREG + 2 * m)) * NC;
    const float4 ka0 = ((const float4*)(K + r0))[t];
    const float4 ka1 = ((const float4*)(K + r0 + NC))[t];
    const float4 kb0 = ((const float4*)(K + r0 + 2 * NC))[t];
    const float4 kb1 = ((const float4*)(K + r0 + 3 * NC))[t];
    const float4 va0 = ((const float4*)(V + r0))[t];
    const float4 va1 = ((const float4*)(V + r0 + NC))[t];
    const float4 vb0 = ((const float4*)(V + r0 + 2 * NC))[t];
    const float4 vb1 = ((const float4*)(V + r0 + 3 * NC))[t];
    const float4 q0 = ((const float4*)q)[t];
    const float4 q1 = ((const float4*)(q + NC))[t]; // q_pool[1]

    // Level-1 partials for both chunks
    float sa0 = dot4(q0, ka0), sa1 = dot4(q0, ka1);
    float sb0 = dot4(q0, kb0), sb1 = dot4(q0, kb1);
    const float4 dva = sub4(va0, va1);
    const float4 dvb = sub4(vb0, vb1);
    float d2a = dot4(dva, dva), d2b = dot4(dvb, dvb);

#pragma unroll
    for (int off = 1; off < 64; off <<= 1) {
        sa0 += __shfl_xor(sa0, off);
        sa1 += __shfl_xor(sa1, off);
        sb0 += __shfl_xor(sb0, off);
        sb1 += __shfl_xor(sb1, off);
        d2a += __shfl_xor(d2a, off);
        d2b += __shfl_xor(d2b, off);
    }
    if (lane == 0) {
        lds[wv] = sa0; lds[4 + wv] = sa1;
        lds[8 + wv] = sb0; lds[12 + wv] = sb1;
        lds[16 + wv] = d2a; lds[20 + wv] = d2b;
    }
    __syncthreads();
    const float Ta0 = lds[0] + lds[1] + lds[2] + lds[3];
    const float Ta1 = lds[4] + lds[5] + lds[6] + lds[7];
    const float Tb0 = lds[8] + lds[9] + lds[10] + lds[11];
    const float Tb1 = lds[12] + lds[13] + lds[14] + lds[15];
    const float Tda = lds[16] + lds[17] + lds[18] + lds[19];
    const float Tdb = lds[20] + lds[21] + lds[22] + lds[23];

    const float wa = 1.0f / (1.0f + __expf(Ta1 - Ta0));
    const float wb = 1.0f / (1.0f + __expf(Tb1 - Tb0));

    const float4 ska = lerp4(wa, ka0, 1.0f - wa, ka1);
    const float4 sva = lerp4(wa, va0, 1.0f - wa, va1);
    const float4 skb = lerp4(wb, kb0, 1.0f - wb, kb1);
    const float4 svb = lerp4(wb, vb0, 1.0f - wb, vb1);

    // K1/V1 rows 2m, 2m+1
    {
        float4* k1p = (float4*)(out + OFF_K1 + ((size_t)b * W1C + 2 * m) * NC);
        float4* v1p = (float4*)(out + OFF_V1 + ((size_t)b * W1C + 2 * m) * NC);
        k1p[t] = ska; k1p[t + NC / 4] = skb;
        v1p[t] = sva; v1p[t + NC / 4] = svb;
    }

    // Level-2 pool on (ska,skb)/(sva,svb) with q_pool[1]
    float e2 = dot4(q1, sub4(ska, skb));
    const float4 dsv = sub4(sva, svb);
    float d22 = dot4(dsv, dsv);
#pragma unroll
    for (int off = 1; off < 64; off <<= 1) {
        e2 += __shfl_xor(e2, off);
        d22 += __shfl_xor(d22, off);
    }
    __syncthreads(); // phase-1 lds fully consumed before overwrite
    if (lane == 0) { lds[wv] = e2; lds[4 + wv] = d22; }
    __syncthreads();
    const float Te2 = lds[0] + lds[1] + lds[2] + lds[3];
    const float Td2 = lds[4] + lds[5] + lds[6] + lds[7];
    const float u0 = 1.0f / (1.0f + __expf(-Te2));

    if (t == 0) {
        const float dwa = wa - 0.5f, dwb = wb - 0.5f, du = u0 - 0.5f;
        ws[b * WS_STRIDE + RB + m] =
            S1F * (dwa * dwa * Tda + dwb * dwb * Tdb) + S2F * du * du * Td2;
    }

    if (m >= NPAIRS - W2C) {
        const int nn = m - (NPAIRS - W2C);
        float4* k2p = (float4*)(out + OFF_K2 + ((size_t)b * W2C + nn) * NC);
        float4* v2p = (float4*)(out + OFF_V2 + ((size_t)b * W2C + nn) * NC);
        k2p[t] = lerp4(u0, ska, 1.0f - u0, skb);
        v2p[t] = lerp4(u0, sva, 1.0f - u0, svb);
    }
}

// Final reduce: one block sums the 1120 pre-scaled partials (deterministic).
__global__ __launch_bounds__(256) void reduce_kernel(const float* __restrict__ ws,
                                                     float* __restrict__ out) {
    const int tid = threadIdx.x;
    float acc = 0.f;
    for (int i = tid; i < NB * WS_STRIDE; i += 256) acc += ws[i];

#pragma unroll
    for (int off = 32; off > 0; off >>= 1) acc += __shfl_down(acc, off);

    __shared__ float red[4];
    if ((tid & 63) == 0) red[tid >> 6] = acc;
    __syncthreads();
    if (tid == 0) out[OFF_R] = red[0] + red[1] + red[2] + red[3];
}

extern "C" void kernel_launch(void* const* d_in, const int* in_sizes, int n_in,
                              void* d_out, int out_size, void* d_ws, size_t ws_size,
                              hipStream_t stream) {
    const float* K = (const float*)d_in[0];
    const float* V = (const float*)d_in[1];
    const float* q = (const float*)d_in[2];
    float* out = (float*)d_out;
    float* ws = (float*)d_ws;

    pool1_kernel<<<dim3(RB + NPB + CPB, NB), 256, 0, stream>>>(K, V, q, out, ws);
    reduce_kernel<<<1, 256, 0, stream>>>(ws, out);
}